// Round 1
// 2316.787 us; speedup vs baseline: 1.3684x; 1.3684x over previous
//
#include <hip/hip_runtime.h>
#include <math.h>

// B=4096 images, P=4096 pixels, F=1024 filters, 50 AdamW steps.
// Round 6: eliminate scratch spill in lca_persistent. Evidence: VGPR_Count=128
// with ~210-reg working set -> 2.09 GB HBM traffic/dispatch (ideal ~60 MB),
// dur == traffic/731GB/s. Restructure: 1024 threads (16 waves, 4/SIMD),
// per-thread state U/M/V = 48 VGPRs, EX moved to LDS (64 KB), acc 16.
// Fits the hard 128-reg cap (16 waves/CU on the 2048-reg pool) -> no spill,
// 2x occupancy. Update math unchanged/same order -> bit-identical outputs.

typedef __bf16 bf16_t;
typedef __bf16 bf16x8 __attribute__((ext_vector_type(8)));
typedef __bf16 bf16x4 __attribute__((ext_vector_type(4)));
typedef float f32x4 __attribute__((ext_vector_type(4)));

__device__ __forceinline__ void async_ld16(const void* g, void* l) {
    __builtin_amdgcn_global_load_lds(
        (const __attribute__((address_space(1))) void*)g,
        (__attribute__((address_space(3))) void*)l, 16, 0, 0);
}

__global__ void cvt_bf16(const float* __restrict__ x, bf16_t* __restrict__ y, long n) {
    long i = ((long)blockIdx.x * blockDim.x + threadIdx.x) * 4;
    if (i + 3 < n) {
        float4 f = *(const float4*)(x + i);
        bf16x4 o = { (bf16_t)f.x, (bf16_t)f.y, (bf16_t)f.z, (bf16_t)f.w };
        *(bf16x4*)(y + i) = o;
    }
}

// PhiT[f][p] = Phi[p][f], fp32 -> bf16.  Phi is [4096,1024].
__global__ void transpose_cvt(const float* __restrict__ src, bf16_t* __restrict__ dst) {
    __shared__ float tile[32][33];
    const int f0 = blockIdx.x * 32;
    const int p0 = blockIdx.y * 32;
    const int tx = threadIdx.x, ty = threadIdx.y;
    for (int r = ty; r < 32; r += 8)
        tile[r][tx] = src[(size_t)(p0 + r) * 1024 + f0 + tx];
    __syncthreads();
    for (int r = ty; r < 32; r += 8)
        dst[(size_t)(f0 + r) * 4096 + p0 + tx] = (bf16_t)tile[tx][r];
}

// C[M,N] = A[M,K] @ BT[N,K]^T (bf16, K-major). 128x128 tile, BK=32.
// MODE 0: store C fp32.  MODE 3: store C bf16 in blocked layout
//   Gblk[row/32][col][row%32]  (requires N==1024).
template<int MODE>
__global__ __launch_bounds__(256) void gemm_bt(
    const bf16_t* __restrict__ A, const bf16_t* __restrict__ BT,
    int M, int N, int K,
    float* __restrict__ Cf, bf16_t* __restrict__ Cb)
{
    __shared__ bf16_t As[128 * 32];
    __shared__ bf16_t Bs[128 * 32];
    const int tid  = threadIdx.x;
    const int n0   = blockIdx.x * 128;
    const int m0   = blockIdx.y * 128;
    const int wave = tid >> 6;
    const int lane = tid & 63;
    const int wm   = (wave >> 1) * 64;
    const int wn   = (wave & 1) * 64;
    const int r0   = tid >> 2;
    const int kc   = (tid & 3) * 8;
    const int lr   = lane >> 4;
    const int lc   = lane & 15;

    f32x4 acc[4][4] = {};
    const size_t arow0 = (size_t)(m0 + r0) * K;
    const size_t arow1 = (size_t)(m0 + 64 + r0) * K;
    const size_t brow0 = (size_t)(n0 + r0) * K;
    const size_t brow1 = (size_t)(n0 + 64 + r0) * K;

    for (int k0 = 0; k0 < K; k0 += 32) {
        async_ld16(A + arow0 + k0 + kc, &As[(size_t)tid * 8]);
        async_ld16(A + arow1 + k0 + kc, &As[(size_t)(tid + 256) * 8]);
        async_ld16(BT + brow0 + k0 + kc, &Bs[(size_t)tid * 8]);
        async_ld16(BT + brow1 + k0 + kc, &Bs[(size_t)(tid + 256) * 8]);
        __syncthreads();
        bf16x8 af[4], bv[4];
#pragma unroll
        for (int i = 0; i < 4; ++i) {
            af[i] = *(const bf16x8*)&As[(wm + i * 16 + lc) * 32 + lr * 8];
            bv[i] = *(const bf16x8*)&Bs[(wn + i * 16 + lc) * 32 + lr * 8];
        }
#pragma unroll
        for (int i = 0; i < 4; ++i)
#pragma unroll
            for (int j = 0; j < 4; ++j)
                acc[i][j] = __builtin_amdgcn_mfma_f32_16x16x32_bf16(af[i], bv[j], acc[i][j], 0, 0, 0);
        __syncthreads();
    }

    // C/D layout: col = lane&15, row = (lane>>4)*4 + reg
#pragma unroll
    for (int i = 0; i < 4; ++i)
#pragma unroll
        for (int t = 0; t < 4; ++t) {
            const int row = m0 + wm + i * 16 + lr * 4 + t;
#pragma unroll
            for (int j = 0; j < 4; ++j) {
                const int col = n0 + wn + j * 16 + lc;
                if constexpr (MODE == 0) {
                    Cf[(size_t)row * N + col] = acc[i][j][t];
                } else {
                    Cb[(size_t)(((row >> 5) << 10) + col) * 32 + (row & 31)] =
                        (bf16_t)acc[i][j][t];
                }
            }
        }
}

// Persistent LCA: each block owns 16 rows for all 50 steps.
// 1024 threads = 16 waves; wave w covers cols [w*64, w*64+64) (4 n-tiles).
// State u,m,v in registers (48 VGPRs); excite in LDS fp32 (64 KB);
// act bf16 in LDS (32 KB, 16B units swizzled: unit ^= (row&7));
// G read from L2 via blocked layout Gblk[k/32][n][k%32] (coalesced 1KB/wave-inst).
// 16 waves/CU => hard cap 128 VGPR/wave; footprint ~110 -> no scratch.
__global__ __launch_bounds__(1024)
void lca_persistent(
    const bf16_t* __restrict__ Gblk, const float* __restrict__ excite,
    float* __restrict__ actsf, bf16_t* __restrict__ actbf)
{
    __shared__ bf16_t act[16 * 1024];   // 32 KB, swizzled
    __shared__ float  exs[16 * 1024];   // 64 KB, exs[row][col] == global layout
    const int tid  = threadIdx.x;
    const int m0   = blockIdx.x * 16;
    const int wave = tid >> 6;
    const int lane = tid & 63;
    const int lr   = lane >> 4;
    const int lc   = lane & 15;
    const int wn   = wave * 64;

    // zero act buffer (act_1 = relu(0 - 0.25) = 0)
    for (int i = tid; i < 16 * 1024 / 8; i += 1024) {
        bf16x8 z = {};
        *(bf16x8*)&act[i * 8] = z;
    }
    // stage excite rows [m0, m0+16) into LDS (contiguous copy, 16B/lane)
    {
        const float* esrc = excite + (size_t)m0 * 1024;
        for (int i = tid; i < 16 * 1024 / 4; i += 1024)
            *(f32x4*)&exs[i * 4] = *(const f32x4*)(esrc + (size_t)i * 4);
    }
    __syncthreads();

    f32x4 U[4] = {}, Mo[4] = {}, Vo[4] = {};

    // per-thread invariant offsets
    const int aoff = lc * 1024;       // act row base (elements)
    const int lcx  = lc & 7;
    int goff[4];
#pragma unroll
    for (int j = 0; j < 4; ++j)
        goff[j] = ((wn + j * 16 + lc) << 5) + lr * 8;

    const float lrate = 0.1f, b1 = 0.9f, b2 = 0.999f, eps = 1e-8f;
    const float wdmul = 1.0f - lrate * 1e-2f;
    float pb1 = 1.0f, pb2 = 1.0f;

    for (int step = 1; step <= 50; ++step) {
        pb1 *= b1; pb2 *= b2;
        const float inv1 = 1.0f / (1.0f - pb1);
        const float inv2 = 1.0f / (1.0f - pb2);

        f32x4 acc[4] = {};
#pragma unroll 2
        for (int kcb = 0; kcb < 32; ++kcb) {
            // A-fragment: act[m = lc][k = kcb*32 + lr*8 + 0..7], swizzled
            const int unit = kcb * 4 + lr;
            const bf16x8 a = *(const bf16x8*)&act[aoff + (((unit ^ lcx)) << 3)];
            const bf16_t* gp = Gblk + ((size_t)kcb << 15);
            bf16x8 b[4];
#pragma unroll
            for (int j = 0; j < 4; ++j)
                b[j] = *(const bf16x8*)(gp + goff[j]);
#pragma unroll
            for (int j = 0; j < 4; ++j)
                acc[j] = __builtin_amdgcn_mfma_f32_16x16x32_bf16(a, b[j], acc[j], 0, 0, 0);
        }
        __syncthreads();   // all waves done reading act

#pragma unroll
        for (int j = 0; j < 4; ++j)
#pragma unroll
            for (int t = 0; t < 4; ++t) {
                const int row = lr * 4 + t;
                const int col = wn + j * 16 + lc;
                const float ex   = exs[row * 1024 + col];
                const float uold = U[j][t];
                const float aold = fmaxf(uold - 0.25f, 0.0f);
                const float g    = uold - ex + acc[j][t] - aold;
                const float mn   = b1 * Mo[j][t] + (1.0f - b1) * g;
                const float vn   = b2 * Vo[j][t] + (1.0f - b2) * g * g;
                float un = uold * wdmul;
                un -= lrate * (mn * inv1) / (sqrtf(vn * inv2) + eps);
                U[j][t] = un; Mo[j][t] = mn; Vo[j][t] = vn;
                const float an = fmaxf(un - 0.25f, 0.0f);
                const int su = (col >> 3) ^ (row & 7);
                act[row * 1024 + (su << 3) + (col & 7)] = (bf16_t)an;
                if (step == 50) {
                    actsf[(size_t)(m0 + row) * 1024 + col] = an;
                    actbf[(size_t)(m0 + row) * 1024 + col] = (bf16_t)an;
                }
            }
        __syncthreads();   // act ready for next step
    }
}

extern "C" void kernel_launch(void* const* d_in, const int* in_sizes, int n_in,
                              void* d_out, int out_size, void* d_ws, size_t ws_size,
                              hipStream_t stream)
{
    const float* images  = (const float*)d_in[0];   // [4096, 4096] (B x P)
    const float* filters = (const float*)d_in[1];   // [4096, 1024] (P x F)
    float* out = (float*)d_out;

    constexpr int B = 4096, P = 4096, F = 1024;
    constexpr size_t BF = (size_t)B * F;   // 4M elems
    constexpr size_t BP = (size_t)B * P;   // 16M elems

    // d_out (80 MB) time-shared:
    //   out[0 : 8M floats)   : xbf (16M bf16)          -> recon overwrites later
    //   out[8M : 12M floats) : excite fp32             -> recon overwrites later
    //   out[16M : 20M floats): acts output (persistent kernel writes it)
    bf16_t* xbf    = (bf16_t*)out;
    float*  excite = out + 2 * BF;
    float*  actsf  = out + BP;

    // d_ws (18 MB): w0 = phiT (8 MB) then actbf ; Gblk (2 MB) ; phibf (8 MB)
    bf16_t* w0    = (bf16_t*)d_ws;
    bf16_t* Gblk  = w0 + BF;               // +8 MB
    bf16_t* phibf = w0 + BF + BF / 4;      // +10 MB

    dim3 blk(256);
    // 1. x -> bf16
    cvt_bf16<<<(unsigned)(BP / 4 / 256), blk, 0, stream>>>(images, xbf, (long)BP);
    // 2. PhiT bf16 [F,P]
    transpose_cvt<<<dim3(F / 32, P / 32), dim3(32, 8), 0, stream>>>(filters, w0);
    // 3. excite = x @ Phi  (A=xbf [B,P], BT=phiT [F,P]) -> fp32 [B,F]
    gemm_bt<0><<<dim3(F / 128, B / 128), blk, 0, stream>>>(
        xbf, w0, B, F, P, excite, nullptr);
    // 4. G = PhiT @ Phi -> blocked bf16 Gblk[k/32][n][k%32]
    gemm_bt<3><<<dim3(F / 128, F / 128), blk, 0, stream>>>(
        w0, w0, F, F, P, nullptr, Gblk);
    // 5. 50 LCA/AdamW steps, persistent. Writes acts fp32 (d_out) + actbf (w0).
    lca_persistent<<<dim3(B / 16), dim3(1024), 0, stream>>>(Gblk, excite, actsf, w0);
    // 6. Phi -> bf16 [P,F]
    cvt_bf16<<<(unsigned)(BF / 4 / 256), blk, 0, stream>>>(filters, phibf, (long)BF);
    // 7. recon = acts @ Phi^T (A=actbf [B,F], BT=phibf [P,F]) -> fp32 [B,P]
    gemm_bt<0><<<dim3(P / 128, B / 128), blk, 0, stream>>>(
        w0, phibf, B, P, F, out, nullptr);
}